// Round 10
// baseline (262.625 us; speedup 1.0000x reference)
//
#include <hip/hip_runtime.h>

#define NODES 50000
#define FEAT  256
#define RELS  4
#define EDGES 80000
#define NEDGE (RELS * EDGES)      // 320000
#define NB    (RELS * NODES)      // 200000 CSR buckets
#define NBSC  196                 // ceil(NB / 1024) scan blocks
#define KSTEPS 40                 // K = 1280 = 40 * 32
#define CHUNKEL ((size_t)NODES * FEAT)

typedef __bf16 bf16x8  __attribute__((ext_vector_type(8)));
typedef float  floatx4 __attribute__((ext_vector_type(4)));

struct BF8U { union { unsigned short u[8]; bf16x8 v; uint4 q; }; };

static __device__ __forceinline__ unsigned short f2bf(float f) {
  union { float f; unsigned u; } v; v.f = f;
  unsigned r = v.u + 0x7FFFu + ((v.u >> 16) & 1u);   // RNE
  return (unsigned short)(r >> 16);
}
static __device__ __forceinline__ bf16x8 cvt8(const float* p, float s) {
  float4 a = ((const float4*)p)[0], b = ((const float4*)p)[1];
  BF8U r;
  r.u[0] = f2bf(a.x * s); r.u[1] = f2bf(a.y * s);
  r.u[2] = f2bf(a.z * s); r.u[3] = f2bf(a.w * s);
  r.u[4] = f2bf(b.x * s); r.u[5] = f2bf(b.y * s);
  r.u[6] = f2bf(b.z * s); r.u[7] = f2bf(b.w * s);
  return r.v;
}

// ===========================================================================
// init: zero cnt + prepack B. One dispatch, independent outputs.
// W (f32) -> bf16 fragment order; uint4 slot g = kc*1024 + nc*64 + lane:
// val j = B[kc*32 + (lane>>4)*8 + j][nc*16 + (lane&15)], B = [W0..W3;Wself]
__global__ __launch_bounds__(256) void init_kernel(const float* __restrict__ w,
                                                   const float* __restrict__ sw,
                                                   unsigned* __restrict__ cnt,
                                                   unsigned short* __restrict__ bpk) {
  int gid = blockIdx.x * 256 + threadIdx.x;
  if (gid < NB) cnt[gid] = 0u;
  if (gid < 40960) {
    int ln = gid & 63, nc = (gid >> 6) & 15, kc = gid >> 10;
    int col = nc * 16 + (ln & 15);
    int row0 = kc * 32 + (ln >> 4) * 8;
    BF8U vv;
#pragma unroll
    for (int j = 0; j < 8; ++j) {
      int gk = row0 + j;
      int c = gk >> 8, kr = gk & 255;
      const float* sp = (c < 4) ? (w + (size_t)c * 65536) : sw;
      vv.u[j] = f2bf(sp[(size_t)kr * 256 + col]);
    }
    ((uint4*)bpk)[gid] = vv.q;
  }
}

__global__ __launch_bounds__(256) void count_kernel(const int* __restrict__ dst,
                                                    unsigned* __restrict__ cnt) {
  int e = blockIdx.x * 256 + threadIdx.x;
  if (e < NEDGE) atomicAdd(&cnt[(e / EDGES) * NODES + dst[e]], 1u);
}

// --- hierarchical exclusive scan (R1/R6 proven 3 coalesced passes) ---------
__global__ __launch_bounds__(256) void scan1_kernel(const unsigned* __restrict__ cnt,
                                                    unsigned* __restrict__ bsum) {
  __shared__ unsigned red[4];
  int t = threadIdx.x;
  int i = blockIdx.x * 1024 + t * 4;
  unsigned s = 0;
  if (i + 3 < NB) {
    uint4 v = *(const uint4*)(cnt + i);
    s = v.x + v.y + v.z + v.w;
  } else {
    for (int j = 0; j < 4; ++j) if (i + j < NB) s += cnt[i + j];
  }
  for (int o = 32; o > 0; o >>= 1) s += __shfl_down(s, o);
  if ((t & 63) == 0) red[t >> 6] = s;
  __syncthreads();
  if (t == 0) bsum[blockIdx.x] = red[0] + red[1] + red[2] + red[3];
}

__global__ __launch_bounds__(256) void scan2_kernel(unsigned* __restrict__ bsum) {
  __shared__ unsigned sa[256], sb[256];
  int t = threadIdx.x;
  unsigned v = (t < NBSC) ? bsum[t] : 0u;
  sa[t] = v;
  __syncthreads();
  unsigned* pin = sa; unsigned* pout = sb;
  for (int d = 1; d < 256; d <<= 1) {
    pout[t] = pin[t] + ((t >= d) ? pin[t - d] : 0u);
    __syncthreads();
    unsigned* tmp = pin; pin = pout; pout = tmp;
  }
  if (t < NBSC) bsum[t] = pin[t] - v;          // exclusive base per scan-block
}

__global__ __launch_bounds__(256) void scan3_kernel(const unsigned* __restrict__ cnt,
                                                    const unsigned* __restrict__ bsum,
                                                    unsigned* __restrict__ off,
                                                    unsigned* __restrict__ cur) {
  __shared__ unsigned sa[256], sb[256];
  int t = threadIdx.x;
  int i = blockIdx.x * 1024 + t * 4;
  uint4 v = {0u, 0u, 0u, 0u};
  if (i + 3 < NB) {
    v = *(const uint4*)(cnt + i);
  } else {
    unsigned tmp[4] = {0u, 0u, 0u, 0u};
    for (int j = 0; j < 4; ++j) if (i + j < NB) tmp[j] = cnt[i + j];
    v.x = tmp[0]; v.y = tmp[1]; v.z = tmp[2]; v.w = tmp[3];
  }
  unsigned s = v.x + v.y + v.z + v.w;
  sa[t] = s;
  __syncthreads();
  unsigned* pin = sa; unsigned* pout = sb;
  for (int d = 1; d < 256; d <<= 1) {
    pout[t] = pin[t] + ((t >= d) ? pin[t - d] : 0u);
    __syncthreads();
    unsigned* tmp = pin; pin = pout; pout = tmp;
  }
  unsigned base = bsum[blockIdx.x] + pin[t] - s;   // global exclusive prefix
  uint4 o;
  o.x = base; o.y = o.x + v.x; o.z = o.y + v.y; o.w = o.z + v.z;
  if (i + 3 < NB) {
    *(uint4*)(off + i) = o;
    *(uint4*)(cur + i) = o;
  } else {
    unsigned oo[4] = {o.x, o.y, o.z, o.w};
    for (int j = 0; j < 4; ++j) if (i + j < NB) { off[i + j] = oo[j]; cur[i + j] = oo[j]; }
  }
  if (blockIdx.x == 0 && t == 0) off[NB] = NEDGE;  // total is statically known
}

__global__ __launch_bounds__(256) void fill_kernel(const int* __restrict__ src,
                                                   const int* __restrict__ dst,
                                                   unsigned* __restrict__ cur,
                                                   unsigned* __restrict__ epk) {
  int e = blockIdx.x * 256 + threadIdx.x;
  if (e < NEDGE) {
    int r = e / EDGES;
    unsigned pos = atomicAdd(&cur[r * NODES + dst[e]], 1u);
    epk[pos] = (unsigned)src[e];
  }
}

// ===========================================================================
// Gather v4: EIGHT buckets per wave (was 4). Gather is a latency ladder
// (~5 dependent memory rounds x ~700cy/wave, 50K waves); halving the wave
// count while doubling in-flight row loads (up to 16/round) halves the
// latency term. One 9-offset load + one epk window (<=64 edges, avg 12.8,
// P(overflow)~0, proven per-bucket fallback). All array indices are
// compile-time constants after unroll (regs, not scratch); bucket conditions
// are wave-uniform (scalar branches). Per-bucket FP order BIT-IDENTICAL to
// the proven pair loop (pairs ascending, A += (u+w), then single).
__global__ __launch_bounds__(256) void gather_kernel(
    const float* __restrict__ x, const unsigned* __restrict__ off,
    const unsigned* __restrict__ epk, unsigned short* __restrict__ agg) {
  const int lane = threadIdx.x & 63;
  const int bid = (blockIdx.x * 4 + (threadIdx.x >> 6)) * 8;  // 8 buckets/wave
  if (bid >= NB) return;

  unsigned ov = (lane < 9) ? off[bid + lane] : 0u;
  unsigned o[9];
#pragma unroll
  for (int j = 0; j < 9; ++j) o[j] = (unsigned)__shfl((int)ov, j);
  const unsigned lo_w = o[0], cnt = o[8] - o[0];

  const float4 fz = {0.f, 0.f, 0.f, 0.f};
  float4 A[8];
#pragma unroll
  for (int j = 0; j < 8; ++j) A[j] = fz;

#define ROW(s) (*(const float4*)(x + (size_t)(s) * FEAT + lane * 4))
#define STORE(j, Av, dcnt)                                                     \
  {                                                                            \
    float sc_ = 1.0f / (float)((dcnt) ? (dcnt) : 1u);                          \
    unsigned short o_[4] = { f2bf((Av).x * sc_), f2bf((Av).y * sc_),           \
                             f2bf((Av).z * sc_), f2bf((Av).w * sc_) };         \
    *(uint2*)(agg + (size_t)(bid + (j)) * FEAT + lane * 4) =                   \
        *(const uint2*)o_;                                                     \
  }

  if (cnt <= 64u) {
    // ---- fast path: whole 8-bucket edge window in one register ------------
    int ev = ((unsigned)lane < cnt) ? (int)epk[lo_w + (unsigned)lane] : 0;
    unsigned e[8], h[8];
#pragma unroll
    for (int j = 0; j < 8; ++j) { e[j] = o[j]; h[j] = o[j + 1]; }
    while (true) {
      bool any = false;
#pragma unroll
      for (int j = 0; j < 8; ++j) any |= (e[j] < h[j]);
      if (!any) break;
      bool q[8], p[8];
      float4 u[8], w[8];
      // round 1: issue up to 16 independent row loads (program order first)
#pragma unroll
      for (int j = 0; j < 8; ++j) {
        q[j] = e[j] < h[j];
        p[j] = e[j] + 2 <= h[j];
        if (q[j]) u[j] = ROW(__shfl(ev, (int)(e[j] - lo_w)));
        if (p[j]) w[j] = ROW(__shfl(ev, (int)(e[j] + 1u - lo_w)));
      }
      // round 2: accumulate (pair grouping identical to proven loop)
#pragma unroll
      for (int j = 0; j < 8; ++j) {
        if (p[j]) {
          A[j].x += u[j].x + w[j].x; A[j].y += u[j].y + w[j].y;
          A[j].z += u[j].z + w[j].z; A[j].w += u[j].w + w[j].w;
          e[j] += 2;
        } else if (q[j]) {
          A[j].x += u[j].x; A[j].y += u[j].y;
          A[j].z += u[j].z; A[j].w += u[j].w;
          ++e[j];
        }
      }
    }
#pragma unroll
    for (int j = 0; j < 8; ++j) STORE(j, A[j], o[j + 1] - o[j]);
  } else {
    // ---- rare fallback (>64 edges in 8 buckets): direct pair loop ---------
#pragma unroll
    for (int j = 0; j < 8; ++j) {
      unsigned lo = o[j], hi = o[j + 1];
      float4 acc = fz;
      unsigned e = lo;
      for (; e + 2 <= hi; e += 2) {
        int s0 = (int)epk[e], s1 = (int)epk[e + 1];
        float4 v0 = ROW(s0), v1 = ROW(s1);
        acc.x += v0.x + v1.x; acc.y += v0.y + v1.y;
        acc.z += v0.z + v1.z; acc.w += v0.w + v1.w;
      }
      if (e < hi) {
        float4 v = ROW((int)epk[e]);
        acc.x += v.x; acc.y += v.y; acc.z += v.z; acc.w += v.w;
      }
      STORE(j, acc, hi - lo);
    }
  }
#undef ROW
#undef STORE
}

// ===========================================================================
// GEMM v4 (R9 proven, verbatim): M-tile 128, 4-deep LDS ring pipeline.
__global__ __launch_bounds__(256, 2) void gemm_kernel(
    const unsigned short* __restrict__ agg, const float* __restrict__ x,
    const unsigned short* __restrict__ bpk, const float* __restrict__ bias,
    float* __restrict__ out) {
  __shared__ uint4 sA[4][512];                  // 4-deep ring, 8KB tiles (128rx32k)
  const int tid = threadIdx.x;
  const int lane = tid & 63, wave = tid >> 6;
  const int quad = lane >> 4, l15 = lane & 15;
  const int m0 = blockIdx.x * 128;
  const int nbase = wave * 4;                   // wave's col quarter

  // staging geometry: 2 uint4/thread, rows trow0 and trow0+64, same k-slot
  const int sl = tid & 3;                       // k-slot 0..3 (8 elems each)
  const int trow0 = tid >> 2;                   // 0..63
  const int trow1 = trow0 + 64;                 // 64..127
  int rg0 = m0 + trow0; if (rg0 >= NODES) rg0 = NODES - 1;
  int rg1 = m0 + trow1; if (rg1 >= NODES) rg1 = NODES - 1;
  const int widx0 = trow0 * 4 + (sl ^ ((trow0 >> 1) & 3));
  const int widx1 = trow1 * 4 + (sl ^ ((trow1 >> 1) & 3));
  const int pswz = quad ^ ((l15 >> 1) & 3);     // swizzled read slot

  const uint4* aggu4 = (const uint4*)agg;

  auto loadA = [&](int t, int rg) -> uint4 {
    if (t < 32) {                               // bf16 agg chunks c=0..3
      return aggu4[(size_t)(t >> 3) * (CHUNKEL / 8) + (size_t)rg * 32 +
                   (size_t)((t & 7) * 4 + sl)];
    } else {                                    // f32 x chunk, convert at stage
      BF8U r;
      r.v = cvt8(x + (size_t)rg * 256 + (t & 7) * 32 + sl * 8, 1.0f);
      return r.q;
    }
  };

#define SYNC_TILE()                                                            \
  do {                                                                         \
    asm volatile("s_waitcnt lgkmcnt(0)" ::: "memory");                         \
    __builtin_amdgcn_sched_barrier(0);                                         \
    __builtin_amdgcn_s_barrier();                                              \
    __builtin_amdgcn_sched_barrier(0);                                         \
  } while (0)

#define READ_A(bidx, dst)                                                      \
  { _Pragma("unroll") for (int ms = 0; ms < 8; ++ms)                           \
      dst[ms].q = sA[bidx][(ms * 16 + l15) * 4 + pswz]; }

#define LOAD_B(kc, dst)                                                        \
  {                                                                            \
    _Pragma("unroll") for (int ns = 0; ns < 4; ++ns) {                         \
      BF8U t_; t_.q = bp4[(size_t)(kc) * 1024 + (nbase + ns) * 64 + lane];     \
      dst[ns] = t_.v;                                                          \
    }                                                                          \
  }
#define MFMA32(af, bf)                                                         \
  _Pragma("unroll") for (int ms = 0; ms < 8; ++ms)                             \
    _Pragma("unroll") for (int ns = 0; ns < 4; ++ns)                           \
      acc[ms][ns] = __builtin_amdgcn_mfma_f32_16x16x32_bf16(af[ms].v, bf[ns],  \
                                                            acc[ms][ns], 0, 0, 0);

  floatx4 acc[8][4] = {};
  const uint4* bp4 = (const uint4*)bpk;
  bf16x8 b0[4], b1[4];
  BF8U a[8];

  // prologue: tile 0 into buf0; tiles 1,2 in flight in regs
  uint4 rP0 = loadA(0, rg0), rP1 = loadA(0, rg1);
  uint4 rO0 = loadA(1, rg0), rO1 = loadA(1, rg1);   // odd-stage regs
  uint4 rE0 = loadA(2, rg0), rE1 = loadA(2, rg1);   // even-stage regs
  sA[0][widx0] = rP0; sA[0][widx1] = rP1;
  LOAD_B(0, b0);
  SYNC_TILE();

  for (int kc = 0; kc < KSTEPS; kc += 2) {
    // ---- sub-step t = kc (even): read buf[kc], write tile kc+1, load kc+3
    READ_A(kc & 3, a);
    sA[(kc + 1) & 3][widx0] = rO0;
    sA[(kc + 1) & 3][widx1] = rO1;
    if (kc + 3 < KSTEPS) { rO0 = loadA(kc + 3, rg0); rO1 = loadA(kc + 3, rg1); }
    LOAD_B(kc + 1, b1);
    MFMA32(a, b0);
    SYNC_TILE();

    // ---- sub-step t = kc+1 (odd): read buf[kc+1], write tile kc+2, load kc+4
    READ_A((kc + 1) & 3, a);
    if (kc + 2 < KSTEPS) {
      sA[(kc + 2) & 3][widx0] = rE0;
      sA[(kc + 2) & 3][widx1] = rE1;
      LOAD_B(kc + 2, b0);
    }
    if (kc + 4 < KSTEPS) { rE0 = loadA(kc + 4, rg0); rE1 = loadA(kc + 4, rg1); }
    MFMA32(a, b1);
    SYNC_TILE();
  }
#undef SYNC_TILE
#undef READ_A
#undef LOAD_B
#undef MFMA32

  // epilogue: C/D row = quad*4 + i, col = l15 (proven mapping)
#pragma unroll
  for (int ms = 0; ms < 8; ++ms)
#pragma unroll
    for (int i = 0; i < 4; ++i) {
      int row = m0 + ms * 16 + quad * 4 + i;
      if (row < NODES) {
        float* op = out + (size_t)row * FEAT + wave * 64;
#pragma unroll
        for (int ns = 0; ns < 4; ++ns) {
          int col = ns * 16 + l15;
          op[col] = fmaxf(acc[ms][ns][i] + bias[wave * 64 + col], 0.0f);
        }
      }
    }
}

// ===========================================================================
// Fallback (R5's proven monolith) — only if ws_size too small.
#define AROWS 128
#define ASTR  260
#define ABLK  512

__global__ __launch_bounds__(ABLK) void rgcn_fallback(
    const float* __restrict__ x, const int* __restrict__ src,
    const int* __restrict__ dst, const float* __restrict__ w,
    const float* __restrict__ sw, const float* __restrict__ bias,
    float* __restrict__ out) {
  __shared__ float sAgg[AROWS * ASTR];
  __shared__ unsigned short sB[8192];
  __shared__ unsigned sDeg[AROWS];
  const int tid = threadIdx.x, wave = tid >> 6, lane = tid & 63;
  const int quad = lane >> 4, l15 = lane & 15;
  const int m0 = blockIdx.x * AROWS;
  const int wrow = wave * 16;
  floatx4 acc[16] = {};
  const floatx4 fz = {0.f, 0.f, 0.f, 0.f};
  for (int r = 0; r < RELS; ++r) {
    for (int t = tid; t < (AROWS * ASTR) / 4; t += ABLK) ((floatx4*)sAgg)[t] = fz;
    if (tid < AROWS) sDeg[tid] = 0u;
    __syncthreads();
    const int4* sr4 = (const int4*)(src + r * EDGES);
    const int4* dr4 = (const int4*)(dst + r * EDGES);
    for (int i0 = tid; i0 < 20480; i0 += ABLK) {
      int4 d4 = {-1, -1, -1, -1}, s4 = {0, 0, 0, 0};
      if (i0 < EDGES / 4) { d4 = dr4[i0]; s4 = sr4[i0]; }
      int dd[4] = {d4.x, d4.y, d4.z, d4.w};
      int ss[4] = {s4.x, s4.y, s4.z, s4.w};
#pragma unroll
      for (int j = 0; j < 4; ++j) {
        unsigned u = (unsigned)(dd[j] - m0);
        unsigned long long mb = __ballot(u < (unsigned)AROWS);
        while (mb) {
          int jl = (int)__ffsll(mb) - 1; mb &= mb - 1;
          int s = __shfl(ss[j], jl);
          int ul = __shfl((int)u, jl);
          if (lane == 0) atomicAdd(&sDeg[ul], 1u);
          const float* xp = x + (size_t)s * FEAT + lane;
          float* ap = sAgg + ul * ASTR + lane;
#pragma unroll
          for (int k = 0; k < 4; ++k) atomicAdd(ap + k * 64, xp[k * 64]);
        }
      }
    }
    __syncthreads();
    unsigned dg = sDeg[wrow + l15];
    float rs = 1.0f / (float)(dg ? dg : 1u);
    const float* Wc = w + (size_t)r * 65536;
    for (int kc = 0; kc < 8; ++kc) {
      for (int t = tid; t < 1024; t += ABLK) {
        int ln = t & 63, nc = t >> 6;
        const float* wp = Wc + (size_t)(kc * 32 + (ln >> 4) * 8) * 256 + nc * 16 + (ln & 15);
        BF8U vv;
#pragma unroll
        for (int j = 0; j < 8; ++j) vv.u[j] = f2bf(wp[(size_t)j * 256]);
        ((uint4*)sB)[t] = vv.q;
      }
      __syncthreads();
      bf16x8 a = cvt8(&sAgg[(wrow + l15) * ASTR + kc * 32 + quad * 8], rs);
#pragma unroll
      for (int ns = 0; ns < 16; ++ns) {
        BF8U b8; b8.q = ((const uint4*)sB)[ns * 64 + lane];
        acc[ns] = __builtin_amdgcn_mfma_f32_16x16x32_bf16(a, b8.v, acc[ns], 0, 0, 0);
      }
      __syncthreads();
    }
  }
  {
    int row = m0 + wrow + l15;
    if (row >= NODES) row = NODES - 1;
    for (int kc = 0; kc < 8; ++kc) {
      for (int t = tid; t < 1024; t += ABLK) {
        int ln = t & 63, nc = t >> 6;
        const float* wp = sw + (size_t)(kc * 32 + (ln >> 4) * 8) * 256 + nc * 16 + (ln & 15);
        BF8U vv;
#pragma unroll
        for (int j = 0; j < 8; ++j) vv.u[j] = f2bf(wp[(size_t)j * 256]);
        ((uint4*)sB)[t] = vv.q;
      }
      __syncthreads();
      bf16x8 a = cvt8(x + (size_t)row * FEAT + kc * 32 + quad * 8, 1.0f);
#pragma unroll
      for (int ns = 0; ns < 16; ++ns) {
        BF8U b8; b8.q = ((const uint4*)sB)[ns * 64 + lane];
        acc[ns] = __builtin_amdgcn_mfma_f32_16x16x32_bf16(a, b8.v, acc[ns], 0, 0, 0);
      }
      __syncthreads();
    }
  }
#pragma unroll
  for (int i = 0; i < 4; ++i) {
    int row = m0 + wrow + quad * 4 + i;
    if (row < NODES) {
      float* op = out + (size_t)row * FEAT;
#pragma unroll
      for (int ns = 0; ns < 16; ++ns) {
        int col = ns * 16 + l15;
        op[col] = fmaxf(acc[ns][i] + bias[col], 0.0f);
      }
    }
  }
}

// ===========================================================================
extern "C" void kernel_launch(void* const* d_in, const int* in_sizes, int n_in,
                              void* d_out, int out_size, void* d_ws, size_t ws_size,
                              hipStream_t stream) {
  const float* x    = (const float*)d_in[0];
  const int*   src  = (const int*)d_in[1];
  const int*   dst  = (const int*)d_in[2];
  const float* w    = (const float*)d_in[3];
  const float* sw   = (const float*)d_in[4];
  const float* bias = (const float*)d_in[5];
  float*       out  = (float*)d_out;
  char* ws = (char*)d_ws;

  // ws: bpk 655360 | cnt 800000 | off 800016 | cur 800000 | epk 1280000
  //     | bsum 784(+pad) | agg bf16 [4][N][256] 102400000
  const size_t NEED = 106736400;                 // unchanged (proven fit)
  if (ws_size >= NEED) {
    unsigned short* bpk = (unsigned short*)ws;
    unsigned* cnt  = (unsigned*)(ws + 655360);
    unsigned* off  = (unsigned*)(ws + 1455360);
    unsigned* cur  = (unsigned*)(ws + 2255376);
    unsigned* epk  = (unsigned*)(ws + 3055376);
    unsigned* bsum = (unsigned*)(ws + 4335376);
    unsigned short* agg = (unsigned short*)(ws + 4336400);

    init_kernel<<<(NB + 255) / 256, 256, 0, stream>>>(w, sw, cnt, bpk);
    count_kernel<<<(NEDGE + 255) / 256, 256, 0, stream>>>(dst, cnt);
    scan1_kernel<<<NBSC, 256, 0, stream>>>(cnt, bsum);
    scan2_kernel<<<1, 256, 0, stream>>>(bsum);
    scan3_kernel<<<NBSC, 256, 0, stream>>>(cnt, bsum, off, cur);
    fill_kernel<<<(NEDGE + 255) / 256, 256, 0, stream>>>(src, dst, cur, epk);
    gather_kernel<<<(NB + 31) / 32, 256, 0, stream>>>(x, off, epk, agg);
    gemm_kernel<<<(NODES + 127) / 128, 256, 0, stream>>>(agg, x, bpk, bias, out);
  } else {
    rgcn_fallback<<<391, ABLK, 0, stream>>>(x, src, dst, w, sw, bias, out);
  }
}

// Round 12
// 242.903 us; speedup vs baseline: 1.0812x; 1.0812x over previous
//
#include <hip/hip_runtime.h>

#define NODES 50000
#define FEAT  256
#define RELS  4
#define EDGES 80000
#define NEDGE (RELS * EDGES)      // 320000
#define NB    (RELS * NODES)      // 200000 CSR buckets
#define NBSC  196                 // ceil(NB / 1024) scan blocks
#define KSTEPS 40                 // K = 1280 = 40 * 32
#define CHUNKEL ((size_t)NODES * FEAT)

typedef __bf16 bf16x8  __attribute__((ext_vector_type(8)));
typedef float  floatx4 __attribute__((ext_vector_type(4)));

struct BF8U { union { unsigned short u[8]; bf16x8 v; uint4 q; }; };

static __device__ __forceinline__ unsigned short f2bf(float f) {
  union { float f; unsigned u; } v; v.f = f;
  unsigned r = v.u + 0x7FFFu + ((v.u >> 16) & 1u);   // RNE
  return (unsigned short)(r >> 16);
}
static __device__ __forceinline__ bf16x8 cvt8(const float* p, float s) {
  float4 a = ((const float4*)p)[0], b = ((const float4*)p)[1];
  BF8U r;
  r.u[0] = f2bf(a.x * s); r.u[1] = f2bf(a.y * s);
  r.u[2] = f2bf(a.z * s); r.u[3] = f2bf(a.w * s);
  r.u[4] = f2bf(b.x * s); r.u[5] = f2bf(b.y * s);
  r.u[6] = f2bf(b.z * s); r.u[7] = f2bf(b.w * s);
  return r.v;
}

// ===========================================================================
// init: zero cnt + prepack B. One dispatch, independent outputs.
// W (f32) -> bf16 fragment order; uint4 slot g = kc*1024 + nc*64 + lane:
// val j = B[kc*32 + (lane>>4)*8 + j][nc*16 + (lane&15)], B = [W0..W3;Wself]
__global__ __launch_bounds__(256) void init_kernel(const float* __restrict__ w,
                                                   const float* __restrict__ sw,
                                                   unsigned* __restrict__ cnt,
                                                   unsigned short* __restrict__ bpk) {
  int gid = blockIdx.x * 256 + threadIdx.x;
  if (gid < NB) cnt[gid] = 0u;
  if (gid < 40960) {
    int ln = gid & 63, nc = (gid >> 6) & 15, kc = gid >> 10;
    int col = nc * 16 + (ln & 15);
    int row0 = kc * 32 + (ln >> 4) * 8;
    BF8U vv;
#pragma unroll
    for (int j = 0; j < 8; ++j) {
      int gk = row0 + j;
      int c = gk >> 8, kr = gk & 255;
      const float* sp = (c < 4) ? (w + (size_t)c * 65536) : sw;
      vv.u[j] = f2bf(sp[(size_t)kr * 256 + col]);
    }
    ((uint4*)bpk)[gid] = vv.q;
  }
}

__global__ __launch_bounds__(256) void count_kernel(const int* __restrict__ dst,
                                                    unsigned* __restrict__ cnt) {
  int e = blockIdx.x * 256 + threadIdx.x;
  if (e < NEDGE) atomicAdd(&cnt[(e / EDGES) * NODES + dst[e]], 1u);
}

// --- scan pass 1 (proven): per-1024-bucket chunk sums ----------------------
__global__ __launch_bounds__(256) void scan1_kernel(const unsigned* __restrict__ cnt,
                                                    unsigned* __restrict__ bsum) {
  __shared__ unsigned red[4];
  int t = threadIdx.x;
  int i = blockIdx.x * 1024 + t * 4;
  unsigned s = 0;
  if (i + 3 < NB) {
    uint4 v = *(const uint4*)(cnt + i);
    s = v.x + v.y + v.z + v.w;
  } else {
    for (int j = 0; j < 4; ++j) if (i + j < NB) s += cnt[i + j];
  }
  for (int o = 32; o > 0; o >>= 1) s += __shfl_down(s, o);
  if ((t & 63) == 0) red[t >> 6] = s;
  __syncthreads();
  if (t == 0) bsum[blockIdx.x] = red[0] + red[1] + red[2] + red[3];
}

// --- merged scan passes 2+3: each block redundantly prefixes the 196-entry
// bsum (784B, L2-resident, ~1us) then runs scan3's proven local-scan body.
// No inter-block communication; input is scan1's completed bsum. Saves one
// dispatch (~11us) with negligible redundant work (unlike R7's 195-deep
// serial-latency chain, this is one load + LDS scan).
__global__ __launch_bounds__(256) void scan23_kernel(const unsigned* __restrict__ cnt,
                                                     const unsigned* __restrict__ bsum,
                                                     unsigned* __restrict__ off,
                                                     unsigned* __restrict__ cur) {
  __shared__ unsigned sa[256], sb[256];
  __shared__ unsigned sbase;
  const int t = threadIdx.x;
  const int vb = blockIdx.x;

  // ---- redundant scan2: exclusive prefix of bsum at index vb --------------
  {
    unsigned v = (t < NBSC) ? bsum[t] : 0u;
    sa[t] = v;
    __syncthreads();
    unsigned* pin = sa; unsigned* pout = sb;
    for (int d = 1; d < 256; d <<= 1) {
      pout[t] = pin[t] + ((t >= d) ? pin[t - d] : 0u);
      __syncthreads();
      unsigned* tmp = pin; pin = pout; pout = tmp;
    }
    if (t == vb) sbase = pin[t] - v;             // exclusive prefix for vb
    __syncthreads();
  }

  // ---- scan3 local body (proven, verbatim; bsum[vb] -> sbase) -------------
  const int i = vb * 1024 + t * 4;
  uint4 v = {0u, 0u, 0u, 0u};
  if (i + 3 < NB) {
    v = *(const uint4*)(cnt + i);
  } else {
    unsigned tmp[4] = {0u, 0u, 0u, 0u};
    for (int j = 0; j < 4; ++j) if (i + j < NB) tmp[j] = cnt[i + j];
    v.x = tmp[0]; v.y = tmp[1]; v.z = tmp[2]; v.w = tmp[3];
  }
  unsigned s = v.x + v.y + v.z + v.w;
  sa[t] = s;
  __syncthreads();
  unsigned* pin = sa; unsigned* pout = sb;
  for (int d = 1; d < 256; d <<= 1) {
    pout[t] = pin[t] + ((t >= d) ? pin[t - d] : 0u);
    __syncthreads();
    unsigned* tmp = pin; pin = pout; pout = tmp;
  }
  unsigned base = sbase + pin[t] - s;            // global exclusive prefix
  uint4 o;
  o.x = base; o.y = o.x + v.x; o.z = o.y + v.y; o.w = o.z + v.z;
  if (i + 3 < NB) {
    *(uint4*)(off + i) = o;
    *(uint4*)(cur + i) = o;
  } else {
    unsigned oo[4] = {o.x, o.y, o.z, o.w};
    for (int j = 0; j < 4; ++j) if (i + j < NB) { off[i + j] = oo[j]; cur[i + j] = oo[j]; }
  }
  if (vb == 0 && t == 0) off[NB] = NEDGE;        // total is statically known
}

__global__ __launch_bounds__(256) void fill_kernel(const int* __restrict__ src,
                                                   const int* __restrict__ dst,
                                                   unsigned* __restrict__ cur,
                                                   unsigned* __restrict__ epk) {
  int e = blockIdx.x * 256 + threadIdx.x;
  if (e < NEDGE) {
    int r = e / EDGES;
    unsigned pos = atomicAdd(&cur[r * NODES + dst[e]], 1u);
    epk[pos] = (unsigned)src[e];
  }
}

// ===========================================================================
// Gather v3 (R6/R9 proven, verbatim — R10's 8-bucket variant regressed via
// occupancy collapse, reverted): FOUR buckets per wave; one 5-offset load,
// one epk-window preload (<=64 edges, shfl broadcast), 4-bucket merged
// pair-loop (up to 8 x-row loads in flight). Per-bucket FP order BIT-IDENTICAL
// to the proven pair loop.
__global__ __launch_bounds__(256) void gather_kernel(
    const float* __restrict__ x, const unsigned* __restrict__ off,
    const unsigned* __restrict__ epk, unsigned short* __restrict__ agg) {
  const int lane = threadIdx.x & 63;
  const int bid = (blockIdx.x * 4 + (threadIdx.x >> 6)) * 4;  // 4 buckets/wave
  if (bid >= NB) return;

  unsigned ov = (lane < 5) ? off[bid + lane] : 0u;
  const unsigned o0 = (unsigned)__shfl((int)ov, 0);
  const unsigned o1 = (unsigned)__shfl((int)ov, 1);
  const unsigned o2 = (unsigned)__shfl((int)ov, 2);
  const unsigned o3 = (unsigned)__shfl((int)ov, 3);
  const unsigned o4 = (unsigned)__shfl((int)ov, 4);
  const unsigned lo_w = o0, cnt = o4 - o0;

  const float4 fz = {0.f, 0.f, 0.f, 0.f};
  float4 A0 = fz, A1 = fz, A2 = fz, A3 = fz;

#define ROW(s) (*(const float4*)(x + (size_t)(s) * FEAT + lane * 4))
#define STORE(j, A, dcnt)                                                      \
  {                                                                            \
    float sc_ = 1.0f / (float)((dcnt) ? (dcnt) : 1u);                          \
    unsigned short o_[4] = { f2bf((A).x * sc_), f2bf((A).y * sc_),             \
                             f2bf((A).z * sc_), f2bf((A).w * sc_) };           \
    *(uint2*)(agg + (size_t)(bid + (j)) * FEAT + lane * 4) =                   \
        *(const uint2*)o_;                                                     \
  }

  if (cnt <= 64u) {
    // ---- fast path: whole edge window in one register, shfl-broadcast -----
    int ev = ((unsigned)lane < cnt) ? (int)epk[lo_w + (unsigned)lane] : 0;
    unsigned e0 = o0, e1 = o1, e2 = o2, e3 = o3;
    const unsigned h0 = o1, h1 = o2, h2 = o3, h3 = o4;
    while ((e0 < h0) | (e1 < h1) | (e2 < h2) | (e3 < h3)) {
      const bool q0 = e0 < h0, p0 = e0 + 2 <= h0;
      const bool q1 = e1 < h1, p1 = e1 + 2 <= h1;
      const bool q2 = e2 < h2, p2 = e2 + 2 <= h2;
      const bool q3 = e3 < h3, p3 = e3 + 2 <= h3;
      float4 u0, w0, u1, w1, u2, w2, u3, w3;
      if (q0) u0 = ROW(__shfl(ev, (int)(e0 - lo_w)));
      if (p0) w0 = ROW(__shfl(ev, (int)(e0 + 1u - lo_w)));
      if (q1) u1 = ROW(__shfl(ev, (int)(e1 - lo_w)));
      if (p1) w1 = ROW(__shfl(ev, (int)(e1 + 1u - lo_w)));
      if (q2) u2 = ROW(__shfl(ev, (int)(e2 - lo_w)));
      if (p2) w2 = ROW(__shfl(ev, (int)(e2 + 1u - lo_w)));
      if (q3) u3 = ROW(__shfl(ev, (int)(e3 - lo_w)));
      if (p3) w3 = ROW(__shfl(ev, (int)(e3 + 1u - lo_w)));
      if (p0) { A0.x += u0.x + w0.x; A0.y += u0.y + w0.y;
                A0.z += u0.z + w0.z; A0.w += u0.w + w0.w; e0 += 2; }
      else if (q0) { A0.x += u0.x; A0.y += u0.y; A0.z += u0.z; A0.w += u0.w; ++e0; }
      if (p1) { A1.x += u1.x + w1.x; A1.y += u1.y + w1.y;
                A1.z += u1.z + w1.z; A1.w += u1.w + w1.w; e1 += 2; }
      else if (q1) { A1.x += u1.x; A1.y += u1.y; A1.z += u1.z; A1.w += u1.w; ++e1; }
      if (p2) { A2.x += u2.x + w2.x; A2.y += u2.y + w2.y;
                A2.z += u2.z + w2.z; A2.w += u2.w + w2.w; e2 += 2; }
      else if (q2) { A2.x += u2.x; A2.y += u2.y; A2.z += u2.z; A2.w += u2.w; ++e2; }
      if (p3) { A3.x += u3.x + w3.x; A3.y += u3.y + w3.y;
                A3.z += u3.z + w3.z; A3.w += u3.w + w3.w; e3 += 2; }
      else if (q3) { A3.x += u3.x; A3.y += u3.y; A3.z += u3.z; A3.w += u3.w; ++e3; }
    }
    STORE(0, A0, o1 - o0);
    STORE(1, A1, o2 - o1);
    STORE(2, A2, o3 - o2);
    STORE(3, A3, o4 - o3);
  } else {
    // ---- rare fallback (>64 edges in 4 buckets): R1's direct pair loop ----
    unsigned losv[5] = {o0, o1, o2, o3, o4};
    for (int j = 0; j < 4; ++j) {
      unsigned lo = losv[j], hi = losv[j + 1];
      float4 acc = fz;
      unsigned e = lo;
      for (; e + 2 <= hi; e += 2) {
        int s0 = (int)epk[e], s1 = (int)epk[e + 1];
        float4 v0 = ROW(s0), v1 = ROW(s1);
        acc.x += v0.x + v1.x; acc.y += v0.y + v1.y;
        acc.z += v0.z + v1.z; acc.w += v0.w + v1.w;
      }
      if (e < hi) {
        float4 v = ROW((int)epk[e]);
        acc.x += v.x; acc.y += v.y; acc.z += v.z; acc.w += v.w;
      }
      STORE(j, acc, hi - lo);
    }
  }
#undef ROW
#undef STORE
}

// ===========================================================================
// GEMM v4 (R9 proven, verbatim): M-tile 128, 4-deep LDS ring pipeline.
__global__ __launch_bounds__(256, 2) void gemm_kernel(
    const unsigned short* __restrict__ agg, const float* __restrict__ x,
    const unsigned short* __restrict__ bpk, const float* __restrict__ bias,
    float* __restrict__ out) {
  __shared__ uint4 sA[4][512];                  // 4-deep ring, 8KB tiles (128rx32k)
  const int tid = threadIdx.x;
  const int lane = tid & 63, wave = tid >> 6;
  const int quad = lane >> 4, l15 = lane & 15;
  const int m0 = blockIdx.x * 128;
  const int nbase = wave * 4;                   // wave's col quarter

  // staging geometry: 2 uint4/thread, rows trow0 and trow0+64, same k-slot
  const int sl = tid & 3;                       // k-slot 0..3 (8 elems each)
  const int trow0 = tid >> 2;                   // 0..63
  const int trow1 = trow0 + 64;                 // 64..127
  int rg0 = m0 + trow0; if (rg0 >= NODES) rg0 = NODES - 1;
  int rg1 = m0 + trow1; if (rg1 >= NODES) rg1 = NODES - 1;
  const int widx0 = trow0 * 4 + (sl ^ ((trow0 >> 1) & 3));
  const int widx1 = trow1 * 4 + (sl ^ ((trow1 >> 1) & 3));
  const int pswz = quad ^ ((l15 >> 1) & 3);     // swizzled read slot

  const uint4* aggu4 = (const uint4*)agg;

  auto loadA = [&](int t, int rg) -> uint4 {
    if (t < 32) {                               // bf16 agg chunks c=0..3
      return aggu4[(size_t)(t >> 3) * (CHUNKEL / 8) + (size_t)rg * 32 +
                   (size_t)((t & 7) * 4 + sl)];
    } else {                                    // f32 x chunk, convert at stage
      BF8U r;
      r.v = cvt8(x + (size_t)rg * 256 + (t & 7) * 32 + sl * 8, 1.0f);
      return r.q;
    }
  };

#define SYNC_TILE()                                                            \
  do {                                                                         \
    asm volatile("s_waitcnt lgkmcnt(0)" ::: "memory");                         \
    __builtin_amdgcn_sched_barrier(0);                                         \
    __builtin_amdgcn_s_barrier();                                              \
    __builtin_amdgcn_sched_barrier(0);                                         \
  } while (0)

#define READ_A(bidx, dst)                                                      \
  { _Pragma("unroll") for (int ms = 0; ms < 8; ++ms)                           \
      dst[ms].q = sA[bidx][(ms * 16 + l15) * 4 + pswz]; }

#define LOAD_B(kc, dst)                                                        \
  {                                                                            \
    _Pragma("unroll") for (int ns = 0; ns < 4; ++ns) {                         \
      BF8U t_; t_.q = bp4[(size_t)(kc) * 1024 + (nbase + ns) * 64 + lane];     \
      dst[ns] = t_.v;                                                          \
    }                                                                          \
  }
#define MFMA32(af, bf)                                                         \
  _Pragma("unroll") for (int ms = 0; ms < 8; ++ms)                             \
    _Pragma("unroll") for (int ns = 0; ns < 4; ++ns)                           \
      acc[ms][ns] = __builtin_amdgcn_mfma_f32_16x16x32_bf16(af[ms].v, bf[ns],  \
                                                            acc[ms][ns], 0, 0, 0);

  floatx4 acc[8][4] = {};
  const uint4* bp4 = (const uint4*)bpk;
  bf16x8 b0[4], b1[4];
  BF8U a[8];

  // prologue: tile 0 into buf0; tiles 1,2 in flight in regs
  uint4 rP0 = loadA(0, rg0), rP1 = loadA(0, rg1);
  uint4 rO0 = loadA(1, rg0), rO1 = loadA(1, rg1);   // odd-stage regs
  uint4 rE0 = loadA(2, rg0), rE1 = loadA(2, rg1);   // even-stage regs
  sA[0][widx0] = rP0; sA[0][widx1] = rP1;
  LOAD_B(0, b0);
  SYNC_TILE();

  for (int kc = 0; kc < KSTEPS; kc += 2) {
    // ---- sub-step t = kc (even): read buf[kc], write tile kc+1, load kc+3
    READ_A(kc & 3, a);
    sA[(kc + 1) & 3][widx0] = rO0;
    sA[(kc + 1) & 3][widx1] = rO1;
    if (kc + 3 < KSTEPS) { rO0 = loadA(kc + 3, rg0); rO1 = loadA(kc + 3, rg1); }
    LOAD_B(kc + 1, b1);
    MFMA32(a, b0);
    SYNC_TILE();

    // ---- sub-step t = kc+1 (odd): read buf[kc+1], write tile kc+2, load kc+4
    READ_A((kc + 1) & 3, a);
    if (kc + 2 < KSTEPS) {
      sA[(kc + 2) & 3][widx0] = rE0;
      sA[(kc + 2) & 3][widx1] = rE1;
      LOAD_B(kc + 2, b0);
    }
    if (kc + 4 < KSTEPS) { rE0 = loadA(kc + 4, rg0); rE1 = loadA(kc + 4, rg1); }
    MFMA32(a, b1);
    SYNC_TILE();
  }
#undef SYNC_TILE
#undef READ_A
#undef LOAD_B
#undef MFMA32

  // epilogue: C/D row = quad*4 + i, col = l15 (proven mapping)
#pragma unroll
  for (int ms = 0; ms < 8; ++ms)
#pragma unroll
    for (int i = 0; i < 4; ++i) {
      int row = m0 + ms * 16 + quad * 4 + i;
      if (row < NODES) {
        float* op = out + (size_t)row * FEAT + wave * 64;
#pragma unroll
        for (int ns = 0; ns < 4; ++ns) {
          int col = ns * 16 + l15;
          op[col] = fmaxf(acc[ms][ns][i] + bias[wave * 64 + col], 0.0f);
        }
      }
    }
}

// ===========================================================================
// Fallback (R5's proven monolith) — only if ws_size too small.
#define AROWS 128
#define ASTR  260
#define ABLK  512

__global__ __launch_bounds__(ABLK) void rgcn_fallback(
    const float* __restrict__ x, const int* __restrict__ src,
    const int* __restrict__ dst, const float* __restrict__ w,
    const float* __restrict__ sw, const float* __restrict__ bias,
    float* __restrict__ out) {
  __shared__ float sAgg[AROWS * ASTR];
  __shared__ unsigned short sB[8192];
  __shared__ unsigned sDeg[AROWS];
  const int tid = threadIdx.x, wave = tid >> 6, lane = tid & 63;
  const int quad = lane >> 4, l15 = lane & 15;
  const int m0 = blockIdx.x * AROWS;
  const int wrow = wave * 16;
  floatx4 acc[16] = {};
  const floatx4 fz = {0.f, 0.f, 0.f, 0.f};
  for (int r = 0; r < RELS; ++r) {
    for (int t = tid; t < (AROWS * ASTR) / 4; t += ABLK) ((floatx4*)sAgg)[t] = fz;
    if (tid < AROWS) sDeg[tid] = 0u;
    __syncthreads();
    const int4* sr4 = (const int4*)(src + r * EDGES);
    const int4* dr4 = (const int4*)(dst + r * EDGES);
    for (int i0 = tid; i0 < 20480; i0 += ABLK) {
      int4 d4 = {-1, -1, -1, -1}, s4 = {0, 0, 0, 0};
      if (i0 < EDGES / 4) { d4 = dr4[i0]; s4 = sr4[i0]; }
      int dd[4] = {d4.x, d4.y, d4.z, d4.w};
      int ss[4] = {s4.x, s4.y, s4.z, s4.w};
#pragma unroll
      for (int j = 0; j < 4; ++j) {
        unsigned u = (unsigned)(dd[j] - m0);
        unsigned long long mb = __ballot(u < (unsigned)AROWS);
        while (mb) {
          int jl = (int)__ffsll(mb) - 1; mb &= mb - 1;
          int s = __shfl(ss[j], jl);
          int ul = __shfl((int)u, jl);
          if (lane == 0) atomicAdd(&sDeg[ul], 1u);
          const float* xp = x + (size_t)s * FEAT + lane;
          float* ap = sAgg + ul * ASTR + lane;
#pragma unroll
          for (int k = 0; k < 4; ++k) atomicAdd(ap + k * 64, xp[k * 64]);
        }
      }
    }
    __syncthreads();
    unsigned dg = sDeg[wrow + l15];
    float rs = 1.0f / (float)(dg ? dg : 1u);
    const float* Wc = w + (size_t)r * 65536;
    for (int kc = 0; kc < 8; ++kc) {
      for (int t = tid; t < 1024; t += ABLK) {
        int ln = t & 63, nc = t >> 6;
        const float* wp = Wc + (size_t)(kc * 32 + (ln >> 4) * 8) * 256 + nc * 16 + (ln & 15);
        BF8U vv;
#pragma unroll
        for (int j = 0; j < 8; ++j) vv.u[j] = f2bf(wp[(size_t)j * 256]);
        ((uint4*)sB)[t] = vv.q;
      }
      __syncthreads();
      bf16x8 a = cvt8(&sAgg[(wrow + l15) * ASTR + kc * 32 + quad * 8], rs);
#pragma unroll
      for (int ns = 0; ns < 16; ++ns) {
        BF8U b8; b8.q = ((const uint4*)sB)[ns * 64 + lane];
        acc[ns] = __builtin_amdgcn_mfma_f32_16x16x32_bf16(a, b8.v, acc[ns], 0, 0, 0);
      }
      __syncthreads();
    }
  }
  {
    int row = m0 + wrow + l15;
    if (row >= NODES) row = NODES - 1;
    for (int kc = 0; kc < 8; ++kc) {
      for (int t = tid; t < 1024; t += ABLK) {
        int ln = t & 63, nc = t >> 6;
        const float* wp = sw + (size_t)(kc * 32 + (ln >> 4) * 8) * 256 + nc * 16 + (ln & 15);
        BF8U vv;
#pragma unroll
        for (int j = 0; j < 8; ++j) vv.u[j] = f2bf(wp[(size_t)j * 256]);
        ((uint4*)sB)[t] = vv.q;
      }
      __syncthreads();
      bf16x8 a = cvt8(x + (size_t)row * FEAT + kc * 32 + quad * 8, 1.0f);
#pragma unroll
      for (int ns = 0; ns < 16; ++ns) {
        BF8U b8; b8.q = ((const uint4*)sB)[ns * 64 + lane];
        acc[ns] = __builtin_amdgcn_mfma_f32_16x16x32_bf16(a, b8.v, acc[ns], 0, 0, 0);
      }
      __syncthreads();
    }
  }
#pragma unroll
  for (int i = 0; i < 4; ++i) {
    int row = m0 + wrow + quad * 4 + i;
    if (row < NODES) {
      float* op = out + (size_t)row * FEAT;
#pragma unroll
      for (int ns = 0; ns < 16; ++ns) {
        int col = ns * 16 + l15;
        op[col] = fmaxf(acc[ns][i] + bias[col], 0.0f);
      }
    }
  }
}

// ===========================================================================
extern "C" void kernel_launch(void* const* d_in, const int* in_sizes, int n_in,
                              void* d_out, int out_size, void* d_ws, size_t ws_size,
                              hipStream_t stream) {
  const float* x    = (const float*)d_in[0];
  const int*   src  = (const int*)d_in[1];
  const int*   dst  = (const int*)d_in[2];
  const float* w    = (const float*)d_in[3];
  const float* sw   = (const float*)d_in[4];
  const float* bias = (const float*)d_in[5];
  float*       out  = (float*)d_out;
  char* ws = (char*)d_ws;

  // ws: bpk 655360 | cnt 800000 | off 800016 | cur 800000 | epk 1280000
  //     | bsum 784(+pad) | agg bf16 [4][N][256] 102400000
  const size_t NEED = 106736400;                 // unchanged (proven fit)
  if (ws_size >= NEED) {
    unsigned short* bpk = (unsigned short*)ws;
    unsigned* cnt  = (unsigned*)(ws + 655360);
    unsigned* off  = (unsigned*)(ws + 1455360);
    unsigned* cur  = (unsigned*)(ws + 2255376);
    unsigned* epk  = (unsigned*)(ws + 3055376);
    unsigned* bsum = (unsigned*)(ws + 4335376);
    unsigned short* agg = (unsigned short*)(ws + 4336400);

    init_kernel<<<(NB + 255) / 256, 256, 0, stream>>>(w, sw, cnt, bpk);
    count_kernel<<<(NEDGE + 255) / 256, 256, 0, stream>>>(dst, cnt);
    scan1_kernel<<<NBSC, 256, 0, stream>>>(cnt, bsum);
    scan23_kernel<<<NBSC, 256, 0, stream>>>(cnt, bsum, off, cur);
    fill_kernel<<<(NEDGE + 255) / 256, 256, 0, stream>>>(src, dst, cur, epk);
    gather_kernel<<<NB / 16, 256, 0, stream>>>(x, off, epk, agg);
    gemm_kernel<<<(NODES + 127) / 128, 256, 0, stream>>>(agg, x, bpk, bias, out);
  } else {
    rgcn_fallback<<<391, ABLK, 0, stream>>>(x, src, dst, w, sw, bias, out);
  }
}

// Round 13
// 242.742 us; speedup vs baseline: 1.0819x; 1.0007x over previous
//
#include <hip/hip_runtime.h>

#define NODES 50000
#define FEAT  256
#define RELS  4
#define EDGES 80000
#define NEDGE (RELS * EDGES)      // 320000
#define NB    (RELS * NODES)      // 200000 CSR buckets
#define NBSC  196                 // ceil(NB / 1024) scan blocks
#define KSTEPS 40                 // K = 1280 = 40 * 32
#define CHUNKEL ((size_t)NODES * FEAT)

typedef __bf16 bf16x8  __attribute__((ext_vector_type(8)));
typedef float  floatx4 __attribute__((ext_vector_type(4)));

struct BF8U { union { unsigned short u[8]; bf16x8 v; uint4 q; }; };

static __device__ __forceinline__ unsigned short f2bf(float f) {
  union { float f; unsigned u; } v; v.f = f;
  unsigned r = v.u + 0x7FFFu + ((v.u >> 16) & 1u);   // RNE
  return (unsigned short)(r >> 16);
}
static __device__ __forceinline__ bf16x8 cvt8(const float* p, float s) {
  float4 a = ((const float4*)p)[0], b = ((const float4*)p)[1];
  BF8U r;
  r.u[0] = f2bf(a.x * s); r.u[1] = f2bf(a.y * s);
  r.u[2] = f2bf(a.z * s); r.u[3] = f2bf(a.w * s);
  r.u[4] = f2bf(b.x * s); r.u[5] = f2bf(b.y * s);
  r.u[6] = f2bf(b.z * s); r.u[7] = f2bf(b.w * s);
  return r.v;
}

// ===========================================================================
// init: zero cnt + prepack B. One dispatch, independent outputs.
// W (f32) -> bf16 fragment order; uint4 slot g = kc*1024 + nc*64 + lane:
// val j = B[kc*32 + (lane>>4)*8 + j][nc*16 + (lane&15)], B = [W0..W3;Wself]
__global__ __launch_bounds__(256) void init_kernel(const float* __restrict__ w,
                                                   const float* __restrict__ sw,
                                                   unsigned* __restrict__ cnt,
                                                   unsigned short* __restrict__ bpk) {
  int gid = blockIdx.x * 256 + threadIdx.x;
  if (gid < NB) cnt[gid] = 0u;
  if (gid < 40960) {
    int ln = gid & 63, nc = (gid >> 6) & 15, kc = gid >> 10;
    int col = nc * 16 + (ln & 15);
    int row0 = kc * 32 + (ln >> 4) * 8;
    BF8U vv;
#pragma unroll
    for (int j = 0; j < 8; ++j) {
      int gk = row0 + j;
      int c = gk >> 8, kr = gk & 255;
      const float* sp = (c < 4) ? (w + (size_t)c * 65536) : sw;
      vv.u[j] = f2bf(sp[(size_t)kr * 256 + col]);
    }
    ((uint4*)bpk)[gid] = vv.q;
  }
}

__global__ __launch_bounds__(256) void count_kernel(const int* __restrict__ dst,
                                                    unsigned* __restrict__ cnt) {
  int e = blockIdx.x * 256 + threadIdx.x;
  if (e < NEDGE) atomicAdd(&cnt[(e / EDGES) * NODES + dst[e]], 1u);
}

// --- scan pass 1 (proven): per-1024-bucket chunk sums ----------------------
__global__ __launch_bounds__(256) void scan1_kernel(const unsigned* __restrict__ cnt,
                                                    unsigned* __restrict__ bsum) {
  __shared__ unsigned red[4];
  int t = threadIdx.x;
  int i = blockIdx.x * 1024 + t * 4;
  unsigned s = 0;
  if (i + 3 < NB) {
    uint4 v = *(const uint4*)(cnt + i);
    s = v.x + v.y + v.z + v.w;
  } else {
    for (int j = 0; j < 4; ++j) if (i + j < NB) s += cnt[i + j];
  }
  for (int o = 32; o > 0; o >>= 1) s += __shfl_down(s, o);
  if ((t & 63) == 0) red[t >> 6] = s;
  __syncthreads();
  if (t == 0) bsum[blockIdx.x] = red[0] + red[1] + red[2] + red[3];
}

// --- merged scan passes 2+3 (R12 proven): redundant 196-entry prefix + local
// scan. No inter-block communication.
__global__ __launch_bounds__(256) void scan23_kernel(const unsigned* __restrict__ cnt,
                                                     const unsigned* __restrict__ bsum,
                                                     unsigned* __restrict__ off,
                                                     unsigned* __restrict__ cur) {
  __shared__ unsigned sa[256], sb[256];
  __shared__ unsigned sbase;
  const int t = threadIdx.x;
  const int vb = blockIdx.x;

  // ---- redundant scan2: exclusive prefix of bsum at index vb --------------
  {
    unsigned v = (t < NBSC) ? bsum[t] : 0u;
    sa[t] = v;
    __syncthreads();
    unsigned* pin = sa; unsigned* pout = sb;
    for (int d = 1; d < 256; d <<= 1) {
      pout[t] = pin[t] + ((t >= d) ? pin[t - d] : 0u);
      __syncthreads();
      unsigned* tmp = pin; pin = pout; pout = tmp;
    }
    if (t == vb) sbase = pin[t] - v;             // exclusive prefix for vb
    __syncthreads();
  }

  // ---- scan3 local body (proven, verbatim; bsum[vb] -> sbase) -------------
  const int i = vb * 1024 + t * 4;
  uint4 v = {0u, 0u, 0u, 0u};
  if (i + 3 < NB) {
    v = *(const uint4*)(cnt + i);
  } else {
    unsigned tmp[4] = {0u, 0u, 0u, 0u};
    for (int j = 0; j < 4; ++j) if (i + j < NB) tmp[j] = cnt[i + j];
    v.x = tmp[0]; v.y = tmp[1]; v.z = tmp[2]; v.w = tmp[3];
  }
  unsigned s = v.x + v.y + v.z + v.w;
  sa[t] = s;
  __syncthreads();
  unsigned* pin = sa; unsigned* pout = sb;
  for (int d = 1; d < 256; d <<= 1) {
    pout[t] = pin[t] + ((t >= d) ? pin[t - d] : 0u);
    __syncthreads();
    unsigned* tmp = pin; pin = pout; pout = tmp;
  }
  unsigned base = sbase + pin[t] - s;            // global exclusive prefix
  uint4 o;
  o.x = base; o.y = o.x + v.x; o.z = o.y + v.y; o.w = o.z + v.z;
  if (i + 3 < NB) {
    *(uint4*)(off + i) = o;
    *(uint4*)(cur + i) = o;
  } else {
    unsigned oo[4] = {o.x, o.y, o.z, o.w};
    for (int j = 0; j < 4; ++j) if (i + j < NB) { off[i + j] = oo[j]; cur[i + j] = oo[j]; }
  }
  if (vb == 0 && t == 0) off[NB] = NEDGE;        // total is statically known
}

// fill + first-src capture: the edge whose atomicAdd returns pos==off[b] is
// the bucket's FIRST edge (epk[off[b]] == its src); stash it in fs[b] so
// gather can issue the first row load one memory-round earlier. fs aliases
// the dead cnt buffer (last read by scan23) -- NEED unchanged.
__global__ __launch_bounds__(256) void fill_kernel(const int* __restrict__ src,
                                                   const int* __restrict__ dst,
                                                   const unsigned* __restrict__ off,
                                                   unsigned* __restrict__ cur,
                                                   unsigned* __restrict__ epk,
                                                   unsigned* __restrict__ fs) {
  int e = blockIdx.x * 256 + threadIdx.x;
  if (e < NEDGE) {
    int r = e / EDGES;
    int b = r * NODES + dst[e];
    unsigned pos = atomicAdd(&cur[b], 1u);
    unsigned sv = (unsigned)src[e];
    epk[pos] = sv;
    if (pos == off[b]) fs[b] = sv;               // first edge of bucket b
  }
}

// ===========================================================================
// Gather v5 = v3 + first-row early issue. Chain was: R1 off -> R2 epk window
// -> R3 first rows. Now: R1 off+fs (both bid-indexed) -> R2 first rows + epk
// window (concurrent) -> R3 remaining rows. Saves one ~700cy dependent round
// for the deg<=2 buckets that dominate (avg deg 1.6). Accumulation VALUES and
// ORDER are bit-identical to v3 (fs[b] == epk[off[b]]; first pair still
// accumulates row(e0)+row(e1) in edge order -- only issue time moves).
__global__ __launch_bounds__(256) void gather_kernel(
    const float* __restrict__ x, const unsigned* __restrict__ off,
    const unsigned* __restrict__ epk, const unsigned* __restrict__ fs,
    unsigned short* __restrict__ agg) {
  const int lane = threadIdx.x & 63;
  const int bid = (blockIdx.x * 4 + (threadIdx.x >> 6)) * 4;  // 4 buckets/wave
  if (bid >= NB) return;

  // R1: offsets AND first-src, both indexable by bid alone
  unsigned ov = (lane < 5) ? off[bid + lane] : 0u;
  unsigned fv = (lane < 4) ? fs[bid + lane] : 0u;
  const unsigned o0 = (unsigned)__shfl((int)ov, 0);
  const unsigned o1 = (unsigned)__shfl((int)ov, 1);
  const unsigned o2 = (unsigned)__shfl((int)ov, 2);
  const unsigned o3 = (unsigned)__shfl((int)ov, 3);
  const unsigned o4 = (unsigned)__shfl((int)ov, 4);
  const int f0 = __shfl((int)fv, 0), f1 = __shfl((int)fv, 1);
  const int f2 = __shfl((int)fv, 2), f3 = __shfl((int)fv, 3);
  const unsigned lo_w = o0, cnt = o4 - o0;

  const float4 fz = {0.f, 0.f, 0.f, 0.f};
  float4 A0 = fz, A1 = fz, A2 = fz, A3 = fz;

#define ROW(s) (*(const float4*)(x + (size_t)(s) * FEAT + lane * 4))
#define STORE(j, A, dcnt)                                                      \
  {                                                                            \
    float sc_ = 1.0f / (float)((dcnt) ? (dcnt) : 1u);                          \
    unsigned short o_[4] = { f2bf((A).x * sc_), f2bf((A).y * sc_),             \
                             f2bf((A).z * sc_), f2bf((A).w * sc_) };           \
    *(uint2*)(agg + (size_t)(bid + (j)) * FEAT + lane * 4) =                   \
        *(const uint2*)o_;                                                     \
  }

  if (cnt <= 64u) {
    // ---- R2: issue first rows (from fs) + epk window, concurrently --------
    const bool q0 = o1 > o0, p0 = o0 + 2 <= o1;
    const bool q1 = o2 > o1, p1 = o1 + 2 <= o2;
    const bool q2 = o3 > o2, p2 = o2 + 2 <= o3;
    const bool q3 = o4 > o3, p3 = o3 + 2 <= o4;
    float4 uf0, uf1, uf2, uf3;
    if (q0) uf0 = ROW(f0);
    if (q1) uf1 = ROW(f1);
    if (q2) uf2 = ROW(f2);
    if (q3) uf3 = ROW(f3);
    int ev = ((unsigned)lane < cnt) ? (int)epk[lo_w + (unsigned)lane] : 0;

    // ---- first pair: u from fs-load, w from window (order preserved) ------
    float4 w0f, w1f, w2f, w3f;
    if (p0) w0f = ROW(__shfl(ev, (int)(o0 + 1u - lo_w)));
    if (p1) w1f = ROW(__shfl(ev, (int)(o1 + 1u - lo_w)));
    if (p2) w2f = ROW(__shfl(ev, (int)(o2 + 1u - lo_w)));
    if (p3) w3f = ROW(__shfl(ev, (int)(o3 + 1u - lo_w)));
    unsigned e0 = o0, e1 = o1, e2 = o2, e3 = o3;
    if (p0) { A0.x += uf0.x + w0f.x; A0.y += uf0.y + w0f.y;
              A0.z += uf0.z + w0f.z; A0.w += uf0.w + w0f.w; e0 += 2; }
    else if (q0) { A0.x += uf0.x; A0.y += uf0.y; A0.z += uf0.z; A0.w += uf0.w; ++e0; }
    if (p1) { A1.x += uf1.x + w1f.x; A1.y += uf1.y + w1f.y;
              A1.z += uf1.z + w1f.z; A1.w += uf1.w + w1f.w; e1 += 2; }
    else if (q1) { A1.x += uf1.x; A1.y += uf1.y; A1.z += uf1.z; A1.w += uf1.w; ++e1; }
    if (p2) { A2.x += uf2.x + w2f.x; A2.y += uf2.y + w2f.y;
              A2.z += uf2.z + w2f.z; A2.w += uf2.w + w2f.w; e2 += 2; }
    else if (q2) { A2.x += uf2.x; A2.y += uf2.y; A2.z += uf2.z; A2.w += uf2.w; ++e2; }
    if (p3) { A3.x += uf3.x + w3f.x; A3.y += uf3.y + w3f.y;
              A3.z += uf3.z + w3f.z; A3.w += uf3.w + w3f.w; e3 += 2; }
    else if (q3) { A3.x += uf3.x; A3.y += uf3.y; A3.z += uf3.z; A3.w += uf3.w; ++e3; }

    // ---- remaining edges: v3's proven merged pair-loop, verbatim ----------
    const unsigned h0 = o1, h1 = o2, h2 = o3, h3 = o4;
    while ((e0 < h0) | (e1 < h1) | (e2 < h2) | (e3 < h3)) {
      const bool r0 = e0 < h0, s0 = e0 + 2 <= h0;
      const bool r1 = e1 < h1, s1 = e1 + 2 <= h1;
      const bool r2 = e2 < h2, s2 = e2 + 2 <= h2;
      const bool r3 = e3 < h3, s3 = e3 + 2 <= h3;
      float4 u0, w0, u1, w1, u2, w2, u3, w3;
      if (r0) u0 = ROW(__shfl(ev, (int)(e0 - lo_w)));
      if (s0) w0 = ROW(__shfl(ev, (int)(e0 + 1u - lo_w)));
      if (r1) u1 = ROW(__shfl(ev, (int)(e1 - lo_w)));
      if (s1) w1 = ROW(__shfl(ev, (int)(e1 + 1u - lo_w)));
      if (r2) u2 = ROW(__shfl(ev, (int)(e2 - lo_w)));
      if (s2) w2 = ROW(__shfl(ev, (int)(e2 + 1u - lo_w)));
      if (r3) u3 = ROW(__shfl(ev, (int)(e3 - lo_w)));
      if (s3) w3 = ROW(__shfl(ev, (int)(e3 + 1u - lo_w)));
      if (s0) { A0.x += u0.x + w0.x; A0.y += u0.y + w0.y;
                A0.z += u0.z + w0.z; A0.w += u0.w + w0.w; e0 += 2; }
      else if (r0) { A0.x += u0.x; A0.y += u0.y; A0.z += u0.z; A0.w += u0.w; ++e0; }
      if (s1) { A1.x += u1.x + w1.x; A1.y += u1.y + w1.y;
                A1.z += u1.z + w1.z; A1.w += u1.w + w1.w; e1 += 2; }
      else if (r1) { A1.x += u1.x; A1.y += u1.y; A1.z += u1.z; A1.w += u1.w; ++e1; }
      if (s2) { A2.x += u2.x + w2.x; A2.y += u2.y + w2.y;
                A2.z += u2.z + w2.z; A2.w += u2.w + w2.w; e2 += 2; }
      else if (r2) { A2.x += u2.x; A2.y += u2.y; A2.z += u2.z; A2.w += u2.w; ++e2; }
      if (s3) { A3.x += u3.x + w3.x; A3.y += u3.y + w3.y;
                A3.z += u3.z + w3.z; A3.w += u3.w + w3.w; e3 += 2; }
      else if (r3) { A3.x += u3.x; A3.y += u3.y; A3.z += u3.z; A3.w += u3.w; ++e3; }
    }
    STORE(0, A0, o1 - o0);
    STORE(1, A1, o2 - o1);
    STORE(2, A2, o3 - o2);
    STORE(3, A3, o4 - o3);
  } else {
    // ---- rare fallback (>64 edges in 4 buckets): R1's direct pair loop ----
    unsigned losv[5] = {o0, o1, o2, o3, o4};
    for (int j = 0; j < 4; ++j) {
      unsigned lo = losv[j], hi = losv[j + 1];
      float4 acc = fz;
      unsigned e = lo;
      for (; e + 2 <= hi; e += 2) {
        int s0 = (int)epk[e], s1 = (int)epk[e + 1];
        float4 v0 = ROW(s0), v1 = ROW(s1);
        acc.x += v0.x + v1.x; acc.y += v0.y + v1.y;
        acc.z += v0.z + v1.z; acc.w += v0.w + v1.w;
      }
      if (e < hi) {
        float4 v = ROW((int)epk[e]);
        acc.x += v.x; acc.y += v.y; acc.z += v.z; acc.w += v.w;
      }
      STORE(j, acc, hi - lo);
    }
  }
#undef ROW
#undef STORE
}

// ===========================================================================
// GEMM v4 (R9 proven, verbatim): M-tile 128, 4-deep LDS ring pipeline.
__global__ __launch_bounds__(256, 2) void gemm_kernel(
    const unsigned short* __restrict__ agg, const float* __restrict__ x,
    const unsigned short* __restrict__ bpk, const float* __restrict__ bias,
    float* __restrict__ out) {
  __shared__ uint4 sA[4][512];                  // 4-deep ring, 8KB tiles (128rx32k)
  const int tid = threadIdx.x;
  const int lane = tid & 63, wave = tid >> 6;
  const int quad = lane >> 4, l15 = lane & 15;
  const int m0 = blockIdx.x * 128;
  const int nbase = wave * 4;                   // wave's col quarter

  // staging geometry: 2 uint4/thread, rows trow0 and trow0+64, same k-slot
  const int sl = tid & 3;                       // k-slot 0..3 (8 elems each)
  const int trow0 = tid >> 2;                   // 0..63
  const int trow1 = trow0 + 64;                 // 64..127
  int rg0 = m0 + trow0; if (rg0 >= NODES) rg0 = NODES - 1;
  int rg1 = m0 + trow1; if (rg1 >= NODES) rg1 = NODES - 1;
  const int widx0 = trow0 * 4 + (sl ^ ((trow0 >> 1) & 3));
  const int widx1 = trow1 * 4 + (sl ^ ((trow1 >> 1) & 3));
  const int pswz = quad ^ ((l15 >> 1) & 3);     // swizzled read slot

  const uint4* aggu4 = (const uint4*)agg;

  auto loadA = [&](int t, int rg) -> uint4 {
    if (t < 32) {                               // bf16 agg chunks c=0..3
      return aggu4[(size_t)(t >> 3) * (CHUNKEL / 8) + (size_t)rg * 32 +
                   (size_t)((t & 7) * 4 + sl)];
    } else {                                    // f32 x chunk, convert at stage
      BF8U r;
      r.v = cvt8(x + (size_t)rg * 256 + (t & 7) * 32 + sl * 8, 1.0f);
      return r.q;
    }
  };

#define SYNC_TILE()                                                            \
  do {                                                                         \
    asm volatile("s_waitcnt lgkmcnt(0)" ::: "memory");                         \
    __builtin_amdgcn_sched_barrier(0);                                         \
    __builtin_amdgcn_s_barrier();                                              \
    __builtin_amdgcn_sched_barrier(0);                                         \
  } while (0)

#define READ_A(bidx, dst)                                                      \
  { _Pragma("unroll") for (int ms = 0; ms < 8; ++ms)                           \
      dst[ms].q = sA[bidx][(ms * 16 + l15) * 4 + pswz]; }

#define LOAD_B(kc, dst)                                                        \
  {                                                                            \
    _Pragma("unroll") for (int ns = 0; ns < 4; ++ns) {                         \
      BF8U t_; t_.q = bp4[(size_t)(kc) * 1024 + (nbase + ns) * 64 + lane];     \
      dst[ns] = t_.v;                                                          \
    }                                                                          \
  }
#define MFMA32(af, bf)                                                         \
  _Pragma("unroll") for (int ms = 0; ms < 8; ++ms)                             \
    _Pragma("unroll") for (int ns = 0; ns < 4; ++ns)                           \
      acc[ms][ns] = __builtin_amdgcn_mfma_f32_16x16x32_bf16(af[ms].v, bf[ns],  \
                                                            acc[ms][ns], 0, 0, 0);

  floatx4 acc[8][4] = {};
  const uint4* bp4 = (const uint4*)bpk;
  bf16x8 b0[4], b1[4];
  BF8U a[8];

  // prologue: tile 0 into buf0; tiles 1,2 in flight in regs
  uint4 rP0 = loadA(0, rg0), rP1 = loadA(0, rg1);
  uint4 rO0 = loadA(1, rg0), rO1 = loadA(1, rg1);   // odd-stage regs
  uint4 rE0 = loadA(2, rg0), rE1 = loadA(2, rg1);   // even-stage regs
  sA[0][widx0] = rP0; sA[0][widx1] = rP1;
  LOAD_B(0, b0);
  SYNC_TILE();

  for (int kc = 0; kc < KSTEPS; kc += 2) {
    // ---- sub-step t = kc (even): read buf[kc], write tile kc+1, load kc+3
    READ_A(kc & 3, a);
    sA[(kc + 1) & 3][widx0] = rO0;
    sA[(kc + 1) & 3][widx1] = rO1;
    if (kc + 3 < KSTEPS) { rO0 = loadA(kc + 3, rg0); rO1 = loadA(kc + 3, rg1); }
    LOAD_B(kc + 1, b1);
    MFMA32(a, b0);
    SYNC_TILE();

    // ---- sub-step t = kc+1 (odd): read buf[kc+1], write tile kc+2, load kc+4
    READ_A((kc + 1) & 3, a);
    if (kc + 2 < KSTEPS) {
      sA[(kc + 2) & 3][widx0] = rE0;
      sA[(kc + 2) & 3][widx1] = rE1;
      LOAD_B(kc + 2, b0);
    }
    if (kc + 4 < KSTEPS) { rE0 = loadA(kc + 4, rg0); rE1 = loadA(kc + 4, rg1); }
    MFMA32(a, b1);
    SYNC_TILE();
  }
#undef SYNC_TILE
#undef READ_A
#undef LOAD_B
#undef MFMA32

  // epilogue: C/D row = quad*4 + i, col = l15 (proven mapping)
#pragma unroll
  for (int ms = 0; ms < 8; ++ms)
#pragma unroll
    for (int i = 0; i < 4; ++i) {
      int row = m0 + ms * 16 + quad * 4 + i;
      if (row < NODES) {
        float* op = out + (size_t)row * FEAT + wave * 64;
#pragma unroll
        for (int ns = 0; ns < 4; ++ns) {
          int col = ns * 16 + l15;
          op[col] = fmaxf(acc[ms][ns][i] + bias[wave * 64 + col], 0.0f);
        }
      }
    }
}

// ===========================================================================
// Fallback (R5's proven monolith) — only if ws_size too small.
#define AROWS 128
#define ASTR  260
#define ABLK  512

__global__ __launch_bounds__(ABLK) void rgcn_fallback(
    const float* __restrict__ x, const int* __restrict__ src,
    const int* __restrict__ dst, const float* __restrict__ w,
    const float* __restrict__ sw, const float* __restrict__ bias,
    float* __restrict__ out) {
  __shared__ float sAgg[AROWS * ASTR];
  __shared__ unsigned short sB[8192];
  __shared__ unsigned sDeg[AROWS];
  const int tid = threadIdx.x, wave = tid >> 6, lane = tid & 63;
  const int quad = lane >> 4, l15 = lane & 15;
  const int m0 = blockIdx.x * AROWS;
  const int wrow = wave * 16;
  floatx4 acc[16] = {};
  const floatx4 fz = {0.f, 0.f, 0.f, 0.f};
  for (int r = 0; r < RELS; ++r) {
    for (int t = tid; t < (AROWS * ASTR) / 4; t += ABLK) ((floatx4*)sAgg)[t] = fz;
    if (tid < AROWS) sDeg[tid] = 0u;
    __syncthreads();
    const int4* sr4 = (const int4*)(src + r * EDGES);
    const int4* dr4 = (const int4*)(dst + r * EDGES);
    for (int i0 = tid; i0 < 20480; i0 += ABLK) {
      int4 d4 = {-1, -1, -1, -1}, s4 = {0, 0, 0, 0};
      if (i0 < EDGES / 4) { d4 = dr4[i0]; s4 = sr4[i0]; }
      int dd[4] = {d4.x, d4.y, d4.z, d4.w};
      int ss[4] = {s4.x, s4.y, s4.z, s4.w};
#pragma unroll
      for (int j = 0; j < 4; ++j) {
        unsigned u = (unsigned)(dd[j] - m0);
        unsigned long long mb = __ballot(u < (unsigned)AROWS);
        while (mb) {
          int jl = (int)__ffsll(mb) - 1; mb &= mb - 1;
          int s = __shfl(ss[j], jl);
          int ul = __shfl((int)u, jl);
          if (lane == 0) atomicAdd(&sDeg[ul], 1u);
          const float* xp = x + (size_t)s * FEAT + lane;
          float* ap = sAgg + ul * ASTR + lane;
#pragma unroll
          for (int k = 0; k < 4; ++k) atomicAdd(ap + k * 64, xp[k * 64]);
        }
      }
    }
    __syncthreads();
    unsigned dg = sDeg[wrow + l15];
    float rs = 1.0f / (float)(dg ? dg : 1u);
    const float* Wc = w + (size_t)r * 65536;
    for (int kc = 0; kc < 8; ++kc) {
      for (int t = tid; t < 1024; t += ABLK) {
        int ln = t & 63, nc = t >> 6;
        const float* wp = Wc + (size_t)(kc * 32 + (ln >> 4) * 8) * 256 + nc * 16 + (ln & 15);
        BF8U vv;
#pragma unroll
        for (int j = 0; j < 8; ++j) vv.u[j] = f2bf(wp[(size_t)j * 256]);
        ((uint4*)sB)[t] = vv.q;
      }
      __syncthreads();
      bf16x8 a = cvt8(&sAgg[(wrow + l15) * ASTR + kc * 32 + quad * 8], rs);
#pragma unroll
      for (int ns = 0; ns < 16; ++ns) {
        BF8U b8; b8.q = ((const uint4*)sB)[ns * 64 + lane];
        acc[ns] = __builtin_amdgcn_mfma_f32_16x16x32_bf16(a, b8.v, acc[ns], 0, 0, 0);
      }
      __syncthreads();
    }
  }
  {
    int row = m0 + wrow + l15;
    if (row >= NODES) row = NODES - 1;
    for (int kc = 0; kc < 8; ++kc) {
      for (int t = tid; t < 1024; t += ABLK) {
        int ln = t & 63, nc = t >> 6;
        const float* wp = sw + (size_t)(kc * 32 + (ln >> 4) * 8) * 256 + nc * 16 + (ln & 15);
        BF8U vv;
#pragma unroll
        for (int j = 0; j < 8; ++j) vv.u[j] = f2bf(wp[(size_t)j * 256]);
        ((uint4*)sB)[t] = vv.q;
      }
      __syncthreads();
      bf16x8 a = cvt8(x + (size_t)row * FEAT + kc * 32 + quad * 8, 1.0f);
#pragma unroll
      for (int ns = 0; ns < 16; ++ns) {
        BF8U b8; b8.q = ((const uint4*)sB)[ns * 64 + lane];
        acc[ns] = __builtin_amdgcn_mfma_f32_16x16x32_bf16(a, b8.v, acc[ns], 0, 0, 0);
      }
      __syncthreads();
    }
  }
#pragma unroll
  for (int i = 0; i < 4; ++i) {
    int row = m0 + wrow + quad * 4 + i;
    if (row < NODES) {
      float* op = out + (size_t)row * FEAT;
#pragma unroll
      for (int ns = 0; ns < 16; ++ns) {
        int col = ns * 16 + l15;
        op[col] = fmaxf(acc[ns][i] + bias[col], 0.0f);
      }
    }
  }
}

// ===========================================================================
extern "C" void kernel_launch(void* const* d_in, const int* in_sizes, int n_in,
                              void* d_out, int out_size, void* d_ws, size_t ws_size,
                              hipStream_t stream) {
  const float* x    = (const float*)d_in[0];
  const int*   src  = (const int*)d_in[1];
  const int*   dst  = (const int*)d_in[2];
  const float* w    = (const float*)d_in[3];
  const float* sw   = (const float*)d_in[4];
  const float* bias = (const float*)d_in[5];
  float*       out  = (float*)d_out;
  char* ws = (char*)d_ws;

  // ws: bpk 655360 | cnt 800000 (reused as fs after scan23) | off 800016
  //     | cur 800000 | epk 1280000 | bsum 784(+pad) | agg bf16 102400000
  const size_t NEED = 106736400;                 // unchanged (proven fit)
  if (ws_size >= NEED) {
    unsigned short* bpk = (unsigned short*)ws;
    unsigned* cnt  = (unsigned*)(ws + 655360);
    unsigned* off  = (unsigned*)(ws + 1455360);
    unsigned* cur  = (unsigned*)(ws + 2255376);
    unsigned* epk  = (unsigned*)(ws + 3055376);
    unsigned* bsum = (unsigned*)(ws + 4335376);
    unsigned short* agg = (unsigned short*)(ws + 4336400);
    unsigned* fs   = cnt;                        // alias: cnt dead after scan23

    init_kernel<<<(NB + 255) / 256, 256, 0, stream>>>(w, sw, cnt, bpk);
    count_kernel<<<(NEDGE + 255) / 256, 256, 0, stream>>>(dst, cnt);
    scan1_kernel<<<NBSC, 256, 0, stream>>>(cnt, bsum);
    scan23_kernel<<<NBSC, 256, 0, stream>>>(cnt, bsum, off, cur);
    fill_kernel<<<(NEDGE + 255) / 256, 256, 0, stream>>>(src, dst, off, cur, epk, fs);
    gather_kernel<<<NB / 16, 256, 0, stream>>>(x, off, epk, fs, agg);
    gemm_kernel<<<(NODES + 127) / 128, 256, 0, stream>>>(agg, x, bpk, bias, out);
  } else {
    rgcn_fallback<<<391, ABLK, 0, stream>>>(x, src, dst, w, sw, bias, out);
  }
}